// Round 1
// baseline (167.810 us; speedup 1.0000x reference)
//
#include <hip/hip_runtime.h>
#include <hip/hip_bf16.h>

typedef __attribute__((ext_vector_type(8))) short short8;
typedef __attribute__((ext_vector_type(4))) short short4v;
typedef __attribute__((ext_vector_type(4))) float f32x4;

#define D_MODEL 1024
#define N_HEADS 16
#define D_KK 64
#define BATCH 4
#define SEQ 1024
#define NTOK (BATCH*SEQ)

// round-to-nearest-even f32 -> bf16 (bit pattern in short)
__device__ __forceinline__ short f2b(float f){
  unsigned u = __float_as_uint(f);
  u += 0x7fffu + ((u >> 16) & 1u);
  return (short)(u >> 16);
}

__device__ __forceinline__ void gl2lds16(const void* g, void* l){
  __builtin_amdgcn_global_load_lds(
      (const __attribute__((address_space(1))) void*)g,
      (__attribute__((address_space(3))) void*)l, 16, 0, 0);
}

// ---------------- f32 -> bf16 conversion ----------------
__global__ __launch_bounds__(256) void cvt_kernel(const float* __restrict__ s,
                                                  short* __restrict__ d, int n){
  int i = (blockIdx.x * 256 + threadIdx.x) * 4;
  if (i >= n) return;
  f32x4 v = *reinterpret_cast<const f32x4*>(s + i);
  short4v o;
  o[0]=f2b(v[0]); o[1]=f2b(v[1]); o[2]=f2b(v[2]); o[3]=f2b(v[3]);
  *reinterpret_cast<short4v*>(d + i) = o;
}

// ---------------- GEMM: C[M,N] = A[M,K] @ W[N,K]^T + bias ----------------
// 128x128 tile, BK=32, 4 waves (2x2), each wave 64x64 (4x4 frags of 16x16x32)
template<bool OUTF32>
__device__ __forceinline__ void gemm_bt_body(const short* __restrict__ A,
    const short* __restrict__ W, const float* __restrict__ bias,
    void* __restrict__ Cout, int N, int K)
{
  __shared__ short As[128][32];
  __shared__ short Bs[128][32];
  const int tid = threadIdx.x, lane = tid & 63, w = tid >> 6;
  const int wr = w >> 1, wc = w & 1;
  const int bn0 = blockIdx.x * 128, bm0 = blockIdx.y * 128;
  const int lrow = lane >> 2, lcol = (lane & 3) * 8;   // staging: 16 rows x 32 elems per 1KB chunk
  const int fr = lane & 15, fk = (lane >> 4) * 8;      // fragment addressing

  f32x4 acc[4][4];
  #pragma unroll
  for (int m=0;m<4;m++)
    #pragma unroll
    for (int n=0;n<4;n++) acc[m][n] = (f32x4){0.f,0.f,0.f,0.f};

  for (int k0 = 0; k0 < K; k0 += 32){
    __syncthreads();
    #pragma unroll
    for (int i=0;i<2;i++){
      const int c = w*2 + i;   // 1KB chunk id, rows [c*16, c*16+16)
      gl2lds16(A + (size_t)(bm0 + c*16 + lrow)*K + k0 + lcol, &As[c*16][0]);
      gl2lds16(W + (size_t)(bn0 + c*16 + lrow)*K + k0 + lcol, &Bs[c*16][0]);
    }
    __syncthreads();
    short8 af[4], bfr[4];
    #pragma unroll
    for (int m=0;m<4;m++)
      af[m] = *reinterpret_cast<const short8*>(&As[wr*64 + m*16 + fr][fk]);
    #pragma unroll
    for (int n=0;n<4;n++)
      bfr[n] = *reinterpret_cast<const short8*>(&Bs[wc*64 + n*16 + fr][fk]);
    #pragma unroll
    for (int m=0;m<4;m++)
      #pragma unroll
      for (int n=0;n<4;n++)
        acc[m][n] = __builtin_amdgcn_mfma_f32_16x16x32_bf16(af[m], bfr[n], acc[m][n], 0,0,0);
  }

  const int g4 = lane >> 4;
  #pragma unroll
  for (int n=0;n<4;n++){
    const int col = bn0 + wc*64 + n*16 + fr;
    const float bv = bias[col];
    #pragma unroll
    for (int m=0;m<4;m++){
      const int row0 = bm0 + wr*64 + m*16 + g4*4;
      #pragma unroll
      for (int r=0;r<4;r++){
        float v = acc[m][n][r] + bv;
        if (OUTF32) ((float*)Cout)[(size_t)(row0+r)*N + col] = v;
        else        ((short*)Cout)[(size_t)(row0+r)*N + col] = f2b(v);
      }
    }
  }
}

__global__ __launch_bounds__(256) void qkv_gemm_kernel(
    const short* __restrict__ X,
    const short* __restrict__ Wq, const short* __restrict__ Wk, const short* __restrict__ Wv,
    const float* __restrict__ bq, const float* __restrict__ bk, const float* __restrict__ bv,
    short* __restrict__ Q, short* __restrict__ K, short* __restrict__ V)
{
  const int z = blockIdx.z;
  const short* W = (z == 0) ? Wq : (z == 1) ? Wk : Wv;
  const float* b = (z == 0) ? bq : (z == 1) ? bk : bv;
  short* O       = (z == 0) ? Q  : (z == 1) ? K  : V;
  gemm_bt_body<false>(X, W, b, O, D_MODEL, D_MODEL);
}

__global__ __launch_bounds__(256) void out_gemm_kernel(
    const short* __restrict__ Ctx, const short* __restrict__ Wo,
    const float* __restrict__ bo, float* __restrict__ Out)
{
  gemm_bt_body<true>(Ctx, Wo, bo, Out, D_MODEL, D_MODEL);
}

// ---------------- flash attention with relative-position bias ----------------
// grid: (S/64 q-tiles, B*H). block 256 = 4 waves, each wave owns 16 q-rows.
__global__ __launch_bounds__(256) void attn_kernel(
    const short* __restrict__ Qb, const short* __restrict__ Kb,
    const short* __restrict__ Vb, const int* __restrict__ mask,
    const float* __restrict__ rel_table, short* __restrict__ Ctx)
{
  const int bh = blockIdx.y;
  const int b = bh >> 4, h = bh & 15;
  const int q0 = blockIdx.x * 64;
  const int tid = threadIdx.x, lane = tid & 63, w = tid >> 6;

  __shared__ short Ks[64][64];      // [key][dim]
  __shared__ short Vt[64][64];      // [dim][key]  (transposed V)
  __shared__ short Ps[4][16][64];   // per-wave P tile [qrow][key]
  __shared__ float rel_sh[127];

  for (int i = tid; i < 127; i += 256) rel_sh[i] = rel_table[i * N_HEADS + h];

  const short* Qg = Qb + (size_t)b*SEQ*D_MODEL + h*D_KK;
  const short* Kg = Kb + (size_t)b*SEQ*D_MODEL + h*D_KK;
  const short* Vg = Vb + (size_t)b*SEQ*D_MODEL + h*D_KK;

  const int fr = lane & 15;
  const int fk = (lane >> 4) * 8;

  // Q fragments held in registers for the whole KV loop
  short8 qf[2];
  #pragma unroll
  for (int f=0; f<2; f++)
    qf[f] = *reinterpret_cast<const short8*>(Qg + (size_t)(q0 + w*16 + fr)*D_MODEL + fk + f*32);

  f32x4 ctx[4];
  #pragma unroll
  for (int dt=0; dt<4; dt++) ctx[dt] = (f32x4){0.f,0.f,0.f,0.f};
  float mrun[4], lrun[4];
  #pragma unroll
  for (int r=0;r<4;r++){ mrun[r] = -1e30f; lrun[r] = 0.f; }

  __syncthreads();   // rel_sh visible

  for (int kv0 = 0; kv0 < SEQ; kv0 += 64){
    __syncthreads();   // protect Ks/Vt from previous iteration's readers
    // stage K tile (row-major) via async global->LDS, 1KB per call (8 rows)
    #pragma unroll
    for (int i=0;i<2;i++){
      const int c = w*2 + i;
      gl2lds16(Kg + (size_t)(kv0 + c*8 + (lane>>3))*D_MODEL + (lane&7)*8, &Ks[c*8][0]);
    }
    // stage V transposed: thread t loads V[r][c0..c0+15], writes Vt[c][r]
    {
      const int r  = tid >> 2;
      const int c0 = (tid & 3) * 16;
      const short* vg = Vg + (size_t)(kv0 + r)*D_MODEL + c0;
      short8 v0 = *reinterpret_cast<const short8*>(vg);
      short8 v1 = *reinterpret_cast<const short8*>(vg + 8);
      #pragma unroll
      for (int i=0;i<8;i++) Vt[c0+i][r]   = v0[i];
      #pragma unroll
      for (int i=0;i<8;i++) Vt[c0+8+i][r] = v1[i];
    }
    __syncthreads();

    // QK^T: 4 key-tiles x 2 K-chunks
    f32x4 sc[4];
    #pragma unroll
    for (int kt=0;kt<4;kt++){
      sc[kt] = (f32x4){0.f,0.f,0.f,0.f};
      #pragma unroll
      for (int f=0;f<2;f++){
        short8 kf = *reinterpret_cast<const short8*>(&Ks[kt*16 + fr][fk + f*32]);
        sc[kt] = __builtin_amdgcn_mfma_f32_16x16x32_bf16(qf[f], kf, sc[kt], 0,0,0);
      }
    }

    // scale + relative-position bias + mask
    const int qbase = q0 + w*16 + (lane>>4)*4;
    #pragma unroll
    for (int kt=0;kt<4;kt++){
      const int key = kv0 + kt*16 + fr;
      const int mk = mask[b*SEQ + key];
      #pragma unroll
      for (int r=0;r<4;r++){
        int d = key - (qbase + r) + 63;
        d = d < 0 ? 0 : (d > 126 ? 126 : d);
        float s = sc[kt][r]*0.125f + rel_sh[d];
        sc[kt][r] = (mk == 0) ? -1e9f : s;
      }
    }

    // online softmax, per q-row r (keys live in 16-lane groups)
    #pragma unroll
    for (int r=0;r<4;r++){
      float vmax = fmaxf(fmaxf(sc[0][r],sc[1][r]), fmaxf(sc[2][r],sc[3][r]));
      #pragma unroll
      for (int m=1;m<16;m<<=1) vmax = fmaxf(vmax, __shfl_xor(vmax, m));
      const float mnew = fmaxf(mrun[r], vmax);
      const float corr = __expf(mrun[r] - mnew);
      float psum = 0.f;
      #pragma unroll
      for (int kt=0;kt<4;kt++){
        float p = __expf(sc[kt][r] - mnew);
        sc[kt][r] = p;
        psum += p;
      }
      #pragma unroll
      for (int m=1;m<16;m<<=1) psum += __shfl_xor(psum, m);
      lrun[r] = lrun[r]*corr + psum;
      mrun[r] = mnew;
      #pragma unroll
      for (int dt=0;dt<4;dt++) ctx[dt][r] *= corr;
    }

    // P -> per-wave LDS tile (C-layout -> A-layout transpose via LDS)
    #pragma unroll
    for (int kt=0;kt<4;kt++)
      #pragma unroll
      for (int r=0;r<4;r++)
        Ps[w][(lane>>4)*4 + r][kt*16 + fr] = f2b(sc[kt][r]);

    asm volatile("s_waitcnt lgkmcnt(0)" ::: "memory");  // wave-local LDS W->R ordering

    // PV: ctx[q][d] += P[q][k] * V[k][d]
    short8 pf[2];
    #pragma unroll
    for (int f=0;f<2;f++)
      pf[f] = *reinterpret_cast<const short8*>(&Ps[w][fr][fk + f*32]);
    #pragma unroll
    for (int dt=0;dt<4;dt++)
      #pragma unroll
      for (int f=0;f<2;f++){
        short8 vf = *reinterpret_cast<const short8*>(&Vt[dt*16 + fr][fk + f*32]);
        ctx[dt] = __builtin_amdgcn_mfma_f32_16x16x32_bf16(pf[f], vf, ctx[dt], 0,0,0);
      }
  }

  float rl[4];
  #pragma unroll
  for (int r=0;r<4;r++) rl[r] = 1.f / lrun[r];
  #pragma unroll
  for (int dt=0;dt<4;dt++)
    #pragma unroll
    for (int r=0;r<4;r++){
      const int q = q0 + w*16 + (lane>>4)*4 + r;
      Ctx[(size_t)(b*SEQ + q)*D_MODEL + h*D_KK + dt*16 + fr] = f2b(ctx[dt][r]*rl[r]);
    }
}

// ---------------- launch ----------------
extern "C" void kernel_launch(void* const* d_in, const int* in_sizes, int n_in,
                              void* d_out, int out_size, void* d_ws, size_t ws_size,
                              hipStream_t stream) {
  const float* x    = (const float*)d_in[0];
  const int*   mask = (const int*)  d_in[1];
  const float* wq   = (const float*)d_in[2];
  const float* bq   = (const float*)d_in[3];
  const float* wk   = (const float*)d_in[4];
  const float* bk   = (const float*)d_in[5];
  const float* wv   = (const float*)d_in[6];
  const float* bv   = (const float*)d_in[7];
  const float* wo   = (const float*)d_in[8];
  const float* bo   = (const float*)d_in[9];
  const float* rel  = (const float*)d_in[10];

  // workspace layout (bf16 shorts)
  const size_t NX = (size_t)NTOK * D_MODEL;      // 4194304
  const size_t NW = (size_t)D_MODEL * D_MODEL;   // 1048576
  if (ws_size < (NX + 4*NW + 4*NX) * sizeof(short)) return;  // ~48 MB needed
  short* xb   = (short*)d_ws;
  short* wqb  = xb  + NX;
  short* wkb  = wqb + NW;
  short* wvb  = wkb + NW;
  short* wob  = wvb + NW;
  short* Qb   = wob + NW;
  short* Kb   = Qb  + NX;
  short* Vb   = Kb  + NX;
  short* Ctxb = Vb  + NX;

  cvt_kernel<<<4096, 256, 0, stream>>>(x,  xb,  (int)NX);
  cvt_kernel<<<1024, 256, 0, stream>>>(wq, wqb, (int)NW);
  cvt_kernel<<<1024, 256, 0, stream>>>(wk, wkb, (int)NW);
  cvt_kernel<<<1024, 256, 0, stream>>>(wv, wvb, (int)NW);
  cvt_kernel<<<1024, 256, 0, stream>>>(wo, wob, (int)NW);

  qkv_gemm_kernel<<<dim3(8, 32, 3), 256, 0, stream>>>(
      xb, wqb, wkb, wvb, bq, bk, bv, Qb, Kb, Vb);

  attn_kernel<<<dim3(16, 64), 256, 0, stream>>>(Qb, Kb, Vb, mask, rel, Ctxb);

  out_gemm_kernel<<<dim3(8, 32), 256, 0, stream>>>(Ctxb, wob, bo, (float*)d_out);
}

// Round 2
// 161.303 us; speedup vs baseline: 1.0403x; 1.0403x over previous
//
#include <hip/hip_runtime.h>
#include <hip/hip_bf16.h>

typedef __attribute__((ext_vector_type(8))) short short8;
typedef __attribute__((ext_vector_type(4))) short short4v;
typedef __attribute__((ext_vector_type(4))) float f32x4;

#define D_MODEL 1024
#define N_HEADS 16
#define D_KK 64
#define BATCH 4
#define SEQ 1024
#define NTOK (BATCH*SEQ)

// round-to-nearest-even f32 -> bf16 (bit pattern in short)
__device__ __forceinline__ short f2b(float f){
  unsigned u = __float_as_uint(f);
  u += 0x7fffu + ((u >> 16) & 1u);
  return (short)(u >> 16);
}

__device__ __forceinline__ void gl2lds16(const void* g, void* l){
  __builtin_amdgcn_global_load_lds(
      (const __attribute__((address_space(1))) void*)g,
      (__attribute__((address_space(3))) void*)l, 16, 0, 0);
}

// ---------------- f32 -> bf16 conversion ----------------
__global__ __launch_bounds__(256) void cvt_kernel(const float* __restrict__ s,
                                                  short* __restrict__ d, int n){
  int i = (blockIdx.x * 256 + threadIdx.x) * 4;
  if (i >= n) return;
  f32x4 v = *reinterpret_cast<const f32x4*>(s + i);
  short4v o;
  o[0]=f2b(v[0]); o[1]=f2b(v[1]); o[2]=f2b(v[2]); o[3]=f2b(v[3]);
  *reinterpret_cast<short4v*>(d + i) = o;
}

// ---------------- GEMM: C[M,N] = A[M,K] @ W[N,K]^T + bias ----------------
// 128x128 tile, BK=32, 4 waves (2x2), each wave 64x64 (4x4 frags of 16x16x32)
// MODE 0: bf16 row-major out. MODE 1: f32 row-major out.
// MODE 2: bf16 out transposed per head: Out[((b*16+h)*64 + d)*SEQ + s]
template<int MODE>
__device__ __forceinline__ void gemm_bt_body(const short* __restrict__ A,
    const short* __restrict__ W, const float* __restrict__ bias,
    void* __restrict__ Cout, int N, int K)
{
  __shared__ short As[128][32];
  __shared__ short Bs[128][32];
  const int tid = threadIdx.x, lane = tid & 63, w = tid >> 6;
  const int wr = w >> 1, wc = w & 1;
  const int bn0 = blockIdx.x * 128, bm0 = blockIdx.y * 128;
  const int lrow = lane >> 2, lcol = (lane & 3) * 8;   // staging: 16 rows x 32 elems per 1KB chunk
  const int fr = lane & 15, fk = (lane >> 4) * 8;      // fragment addressing

  f32x4 acc[4][4];
  #pragma unroll
  for (int m=0;m<4;m++)
    #pragma unroll
    for (int n=0;n<4;n++) acc[m][n] = (f32x4){0.f,0.f,0.f,0.f};

  for (int k0 = 0; k0 < K; k0 += 32){
    __syncthreads();
    #pragma unroll
    for (int i=0;i<2;i++){
      const int c = w*2 + i;   // 1KB chunk id, rows [c*16, c*16+16)
      gl2lds16(A + (size_t)(bm0 + c*16 + lrow)*K + k0 + lcol, &As[c*16][0]);
      gl2lds16(W + (size_t)(bn0 + c*16 + lrow)*K + k0 + lcol, &Bs[c*16][0]);
    }
    __syncthreads();
    short8 af[4], bfr[4];
    #pragma unroll
    for (int m=0;m<4;m++)
      af[m] = *reinterpret_cast<const short8*>(&As[wr*64 + m*16 + fr][fk]);
    #pragma unroll
    for (int n=0;n<4;n++)
      bfr[n] = *reinterpret_cast<const short8*>(&Bs[wc*64 + n*16 + fr][fk]);
    #pragma unroll
    for (int m=0;m<4;m++)
      #pragma unroll
      for (int n=0;n<4;n++)
        acc[m][n] = __builtin_amdgcn_mfma_f32_16x16x32_bf16(af[m], bfr[n], acc[m][n], 0,0,0);
  }

  const int g4 = lane >> 4;
  #pragma unroll
  for (int n=0;n<4;n++){
    const int col = bn0 + wc*64 + n*16 + fr;
    const float bv = bias[col];
    if (MODE == 2){
      const int hh = col >> 6, dd = col & 63;
      #pragma unroll
      for (int m=0;m<4;m++){
        const int row0 = bm0 + wr*64 + m*16 + g4*4;   // token, multiple of 4
        const int bb = row0 >> 10, ss = row0 & 1023;
        short4v o;
        #pragma unroll
        for (int r=0;r<4;r++) o[r] = f2b(acc[m][n][r] + bv);
        *reinterpret_cast<short4v*>(
            (short*)Cout + ((size_t)(bb*N_HEADS+hh)*D_KK + dd)*SEQ + ss) = o;
      }
    } else {
      #pragma unroll
      for (int m=0;m<4;m++){
        const int row0 = bm0 + wr*64 + m*16 + g4*4;
        #pragma unroll
        for (int r=0;r<4;r++){
          float v = acc[m][n][r] + bv;
          if (MODE == 1) ((float*)Cout)[(size_t)(row0+r)*N + col] = v;
          else           ((short*)Cout)[(size_t)(row0+r)*N + col] = f2b(v);
        }
      }
    }
  }
}

__global__ __launch_bounds__(256) void qkv_gemm_kernel(
    const short* __restrict__ X,
    const short* __restrict__ Wq, const short* __restrict__ Wk, const short* __restrict__ Wv,
    const float* __restrict__ bq, const float* __restrict__ bk, const float* __restrict__ bv,
    short* __restrict__ Q, short* __restrict__ K, short* __restrict__ V)
{
  const int z = blockIdx.z;
  if (z == 0)      gemm_bt_body<0>(X, Wq, bq, Q, D_MODEL, D_MODEL);
  else if (z == 1) gemm_bt_body<0>(X, Wk, bk, K, D_MODEL, D_MODEL);
  else             gemm_bt_body<2>(X, Wv, bv, V, D_MODEL, D_MODEL);  // V transposed per head
}

__global__ __launch_bounds__(256) void out_gemm_kernel(
    const short* __restrict__ Ctx, const short* __restrict__ Wo,
    const float* __restrict__ bo, float* __restrict__ Out)
{
  gemm_bt_body<1>(Ctx, Wo, bo, Out, D_MODEL, D_MODEL);
}

// ---------------- flash attention with relative-position bias ----------------
// 1-D grid of 1024 blocks, XCD-grouped: all 16 q-tiles of a (b,h) on one XCD.
// block 256 = 4 waves, each wave owns 16 q-rows. KV tiles of 64, double-buffered.
__global__ __launch_bounds__(256) void attn_kernel(
    const short* __restrict__ Qb, const short* __restrict__ Kb,
    const short* __restrict__ Vtg, const int* __restrict__ mask,
    const float* __restrict__ rel_table, short* __restrict__ Ctx)
{
  const int bid = blockIdx.x;
  const int xcd = bid & 7, slot = bid >> 3;
  const int bh = xcd * 8 + (slot >> 4);      // 8 (b,h) groups per XCD
  const int qt = slot & 15;
  const int b = bh >> 4, h = bh & 15;
  const int q0 = qt * 64;
  const int tid = threadIdx.x, lane = tid & 63, w = tid >> 6;

  __shared__ short Ks[2][64][64];   // [key][dim], XOR-swizzled bytes
  __shared__ short Vs[2][64][64];   // [dim][key], XOR-swizzled bytes
  __shared__ short Ps[4][16][64];   // per-wave P tile [qrow][key], XOR-swizzled
  __shared__ float rel_sh[127];

  for (int i = tid; i < 127; i += 256) rel_sh[i] = rel_table[i * N_HEADS + h];

  const short* Qg = Qb + (size_t)b*SEQ*D_MODEL + h*D_KK;
  const short* Kg = Kb + (size_t)b*SEQ*D_MODEL + h*D_KK;
  const short* Vg = Vtg + (size_t)bh*D_KK*SEQ;     // rows = d (stride SEQ)

  const int fr = lane & 15;
  const int fk = (lane >> 4) * 8;

  // Q fragments held in registers for the whole KV loop
  short8 qf[2];
  #pragma unroll
  for (int f=0; f<2; f++)
    qf[f] = *reinterpret_cast<const short8*>(Qg + (size_t)(q0 + w*16 + fr)*D_MODEL + fk + f*32);

  f32x4 ctx[4];
  #pragma unroll
  for (int dt=0; dt<4; dt++) ctx[dt] = (f32x4){0.f,0.f,0.f,0.f};
  float mrun[4], lrun[4];
  #pragma unroll
  for (int r=0;r<4;r++){ mrun[r] = -1e30f; lrun[r] = 0.f; }

  // stage K tile and V^T tile (1KB per gl2lds16 = 8 rows of 128B), source
  // column pre-swizzled so that swizzled reads see the natural layout
  const int srow = lane >> 3;                 // row within 8-row chunk
  const int scol = ((lane & 7) ^ srow) * 8;   // pre-swizzled 16B column
  auto stage = [&](int buf, int kv0){
    #pragma unroll
    for (int i=0;i<2;i++){
      const int c = w*2 + i;                  // chunk id 0..7
      gl2lds16(Kg + (size_t)(kv0 + c*8 + srow)*D_MODEL + scol, &Ks[buf][c*8][0]);
      gl2lds16(Vg + (size_t)(c*8 + srow)*SEQ + kv0 + scol,     &Vs[buf][c*8][0]);
    }
  };

  stage(0, 0);
  __syncthreads();   // rel_sh visible + tile 0 staged (vmcnt drained by barrier)

  int buf = 0;
  for (int t = 0; t < SEQ/64; ++t){
    const int kv0 = t * 64;
    if (t < SEQ/64 - 1) stage(buf ^ 1, kv0 + 64);   // prefetch next tile

    // QK^T: 4 key-tiles x 2 K-chunks (swizzled ds_read_b128)
    const char* ksb = (const char*)&Ks[buf][0][0];
    f32x4 sc[4];
    #pragma unroll
    for (int kt=0;kt<4;kt++){
      sc[kt] = (f32x4){0.f,0.f,0.f,0.f};
      const int rr = kt*16 + fr;
      const int swz = (rr & 7) << 4;
      #pragma unroll
      for (int f=0;f<2;f++){
        short8 kf = *reinterpret_cast<const short8*>(
            ksb + rr*128 + (((lane>>4)*16 + f*64) ^ swz));
        sc[kt] = __builtin_amdgcn_mfma_f32_16x16x32_bf16(qf[f], kf, sc[kt], 0,0,0);
      }
    }

    // scale + relative-position bias + mask
    const int qbase = q0 + w*16 + (lane>>4)*4;
    #pragma unroll
    for (int kt=0;kt<4;kt++){
      const int key = kv0 + kt*16 + fr;
      const int mk = mask[b*SEQ + key];
      #pragma unroll
      for (int r=0;r<4;r++){
        int d = key - (qbase + r) + 63;
        d = d < 0 ? 0 : (d > 126 ? 126 : d);
        float s = sc[kt][r]*0.125f + rel_sh[d];
        sc[kt][r] = (mk == 0) ? -1e9f : s;
      }
    }

    // online softmax, per q-row r (keys live in 16-lane groups)
    #pragma unroll
    for (int r=0;r<4;r++){
      float vmax = fmaxf(fmaxf(sc[0][r],sc[1][r]), fmaxf(sc[2][r],sc[3][r]));
      #pragma unroll
      for (int m=1;m<16;m<<=1) vmax = fmaxf(vmax, __shfl_xor(vmax, m));
      const float mnew = fmaxf(mrun[r], vmax);
      const float corr = __expf(mrun[r] - mnew);
      float psum = 0.f;
      #pragma unroll
      for (int kt=0;kt<4;kt++){
        float p = __expf(sc[kt][r] - mnew);
        sc[kt][r] = p;
        psum += p;
      }
      #pragma unroll
      for (int m=1;m<16;m<<=1) psum += __shfl_xor(psum, m);
      lrun[r] = lrun[r]*corr + psum;
      mrun[r] = mnew;
      #pragma unroll
      for (int dt=0;dt<4;dt++) ctx[dt][r] *= corr;
    }

    // P -> per-wave LDS tile (C-layout -> A-layout transpose), swizzled
    {
      char* psb = (char*)&Ps[w][0][0];
      #pragma unroll
      for (int kt=0;kt<4;kt++)
        #pragma unroll
        for (int r=0;r<4;r++){
          const int qr = (lane>>4)*4 + r;
          *(short*)(psb + qr*128 + ((kt*32 + fr*2) ^ ((qr&7)<<4))) = f2b(sc[kt][r]);
        }
    }
    asm volatile("s_waitcnt lgkmcnt(0)" ::: "memory");  // wave-local LDS W->R ordering

    // PV: ctx[q][d] += P[q][k] * V[k][d]  (all reads swizzled)
    {
      const char* psb = (const char*)&Ps[w][0][0];
      const char* vsb = (const char*)&Vs[buf][0][0];
      short8 pf[2];
      const int pswz = (fr & 7) << 4;
      #pragma unroll
      for (int f=0;f<2;f++)
        pf[f] = *reinterpret_cast<const short8*>(
            psb + fr*128 + (((lane>>4)*16 + f*64) ^ pswz));
      #pragma unroll
      for (int dt=0;dt<4;dt++){
        const int dd = dt*16 + fr;
        const int vswz = (dd & 7) << 4;
        #pragma unroll
        for (int f=0;f<2;f++){
          short8 vf = *reinterpret_cast<const short8*>(
              vsb + dd*128 + (((lane>>4)*16 + f*64) ^ vswz));
          ctx[dt] = __builtin_amdgcn_mfma_f32_16x16x32_bf16(pf[f], vf, ctx[dt], 0,0,0);
        }
      }
    }

    __syncthreads();   // next tile staged (vmcnt drain) + all waves done with buf
    buf ^= 1;
  }

  float rl[4];
  #pragma unroll
  for (int r=0;r<4;r++) rl[r] = 1.f / lrun[r];
  #pragma unroll
  for (int dt=0;dt<4;dt++)
    #pragma unroll
    for (int r=0;r<4;r++){
      const int q = q0 + w*16 + (lane>>4)*4 + r;
      Ctx[(size_t)(b*SEQ + q)*D_MODEL + h*D_KK + dt*16 + fr] = f2b(ctx[dt][r]*rl[r]);
    }
}

// ---------------- launch ----------------
extern "C" void kernel_launch(void* const* d_in, const int* in_sizes, int n_in,
                              void* d_out, int out_size, void* d_ws, size_t ws_size,
                              hipStream_t stream) {
  const float* x    = (const float*)d_in[0];
  const int*   mask = (const int*)  d_in[1];
  const float* wq   = (const float*)d_in[2];
  const float* bq   = (const float*)d_in[3];
  const float* wk   = (const float*)d_in[4];
  const float* bk   = (const float*)d_in[5];
  const float* wv   = (const float*)d_in[6];
  const float* bv   = (const float*)d_in[7];
  const float* wo   = (const float*)d_in[8];
  const float* bo   = (const float*)d_in[9];
  const float* rel  = (const float*)d_in[10];

  // workspace layout (bf16 shorts)
  const size_t NX = (size_t)NTOK * D_MODEL;      // 4194304
  const size_t NW = (size_t)D_MODEL * D_MODEL;   // 1048576
  if (ws_size < (NX + 4*NW + 4*NX) * sizeof(short)) return;  // ~48 MB needed
  short* xb   = (short*)d_ws;
  short* wqb  = xb  + NX;
  short* wkb  = wqb + NW;
  short* wvb  = wkb + NW;
  short* wob  = wvb + NW;
  short* Qb   = wob + NW;
  short* Kb   = Qb  + NX;
  short* Vtg  = Kb  + NX;   // V transposed per head: [B*H][64][SEQ]
  short* Ctxb = Vtg + NX;

  cvt_kernel<<<4096, 256, 0, stream>>>(x,  xb,  (int)NX);
  cvt_kernel<<<1024, 256, 0, stream>>>(wq, wqb, (int)NW);
  cvt_kernel<<<1024, 256, 0, stream>>>(wk, wkb, (int)NW);
  cvt_kernel<<<1024, 256, 0, stream>>>(wv, wvb, (int)NW);
  cvt_kernel<<<1024, 256, 0, stream>>>(wo, wob, (int)NW);

  qkv_gemm_kernel<<<dim3(8, 32, 3), 256, 0, stream>>>(
      xb, wqb, wkb, wvb, bq, bk, bv, Qb, Kb, Vtg);

  attn_kernel<<<1024, 256, 0, stream>>>(Qb, Kb, Vtg, mask, rel, Ctxb);

  out_gemm_kernel<<<dim3(8, 32), 256, 0, stream>>>(Ctxb, wob, bo, (float*)d_out);
}

// Round 3
// 148.113 us; speedup vs baseline: 1.1330x; 1.0891x over previous
//
#include <hip/hip_runtime.h>
#include <hip/hip_bf16.h>

typedef __attribute__((ext_vector_type(8))) short short8;
typedef __attribute__((ext_vector_type(4))) short short4v;
typedef __attribute__((ext_vector_type(4))) float f32x4;

#define D_MODEL 1024
#define N_HEADS 16
#define D_KK 64
#define BATCH 4
#define SEQ 1024
#define NTOK (BATCH*SEQ)

#define LOG2E  1.44269504f
#define SCALE2 (0.125f * 1.44269504f)
#define NEGBIG (-1.44269504e9f)

#if __has_builtin(__builtin_amdgcn_mfma_f32_16x16x16bf16_1k)
#define HAVE_MFMA16 1
#else
#define HAVE_MFMA16 0
#endif

// round-to-nearest-even f32 -> bf16 (bit pattern in short)
__device__ __forceinline__ short f2b(float f){
  unsigned u = __float_as_uint(f);
  u += 0x7fffu + ((u >> 16) & 1u);
  return (short)(u >> 16);
}

__device__ __forceinline__ void gl2lds16(const void* g, void* l){
  __builtin_amdgcn_global_load_lds(
      (const __attribute__((address_space(1))) void*)g,
      (__attribute__((address_space(3))) void*)l, 16, 0, 0);
}

// ---------------- f32 -> bf16 conversion ----------------
__global__ __launch_bounds__(256) void cvt_kernel(const float* __restrict__ s,
                                                  short* __restrict__ d, int n){
  int i = (blockIdx.x * 256 + threadIdx.x) * 4;
  if (i >= n) return;
  f32x4 v = *reinterpret_cast<const f32x4*>(s + i);
  short4v o;
  o[0]=f2b(v[0]); o[1]=f2b(v[1]); o[2]=f2b(v[2]); o[3]=f2b(v[3]);
  *reinterpret_cast<short4v*>(d + i) = o;
}

// ---------------- GEMM: C[M,N] = A[M,K] @ W[N,K]^T + bias ----------------
// 128x128 tile, BK=32, 4 waves (2x2), each wave 64x64 (4x4 frags of 16x16x32)
// MODE 0: bf16 row-major out. MODE 1: f32 row-major out.
// MODE 2: bf16 out transposed per head: Out[((b*16+h)*64 + d)*SEQ + s]
template<int MODE>
__device__ __forceinline__ void gemm_bt_body(const short* __restrict__ A,
    const short* __restrict__ W, const float* __restrict__ bias,
    void* __restrict__ Cout, int N, int K)
{
  __shared__ short As[128][32];
  __shared__ short Bs[128][32];
  const int tid = threadIdx.x, lane = tid & 63, w = tid >> 6;
  const int wr = w >> 1, wc = w & 1;
  const int bn0 = blockIdx.x * 128, bm0 = blockIdx.y * 128;
  const int lrow = lane >> 2, lcol = (lane & 3) * 8;
  const int fr = lane & 15, fk = (lane >> 4) * 8;

  f32x4 acc[4][4];
  #pragma unroll
  for (int m=0;m<4;m++)
    #pragma unroll
    for (int n=0;n<4;n++) acc[m][n] = (f32x4){0.f,0.f,0.f,0.f};

  for (int k0 = 0; k0 < K; k0 += 32){
    __syncthreads();
    #pragma unroll
    for (int i=0;i<2;i++){
      const int c = w*2 + i;
      gl2lds16(A + (size_t)(bm0 + c*16 + lrow)*K + k0 + lcol, &As[c*16][0]);
      gl2lds16(W + (size_t)(bn0 + c*16 + lrow)*K + k0 + lcol, &Bs[c*16][0]);
    }
    __syncthreads();
    short8 af[4], bfr[4];
    #pragma unroll
    for (int m=0;m<4;m++)
      af[m] = *reinterpret_cast<const short8*>(&As[wr*64 + m*16 + fr][fk]);
    #pragma unroll
    for (int n=0;n<4;n++)
      bfr[n] = *reinterpret_cast<const short8*>(&Bs[wc*64 + n*16 + fr][fk]);
    #pragma unroll
    for (int m=0;m<4;m++)
      #pragma unroll
      for (int n=0;n<4;n++)
        acc[m][n] = __builtin_amdgcn_mfma_f32_16x16x32_bf16(af[m], bfr[n], acc[m][n], 0,0,0);
  }

  const int g4 = lane >> 4;
  #pragma unroll
  for (int n=0;n<4;n++){
    const int col = bn0 + wc*64 + n*16 + fr;
    const float bv = bias[col];
    if (MODE == 2){
      const int hh = col >> 6, dd = col & 63;
      #pragma unroll
      for (int m=0;m<4;m++){
        const int row0 = bm0 + wr*64 + m*16 + g4*4;
        const int bb = row0 >> 10, ss = row0 & 1023;
        short4v o;
        #pragma unroll
        for (int r=0;r<4;r++) o[r] = f2b(acc[m][n][r] + bv);
        *reinterpret_cast<short4v*>(
            (short*)Cout + ((size_t)(bb*N_HEADS+hh)*D_KK + dd)*SEQ + ss) = o;
      }
    } else {
      #pragma unroll
      for (int m=0;m<4;m++){
        const int row0 = bm0 + wr*64 + m*16 + g4*4;
        #pragma unroll
        for (int r=0;r<4;r++){
          float v = acc[m][n][r] + bv;
          if (MODE == 1) ((float*)Cout)[(size_t)(row0+r)*N + col] = v;
          else           ((short*)Cout)[(size_t)(row0+r)*N + col] = f2b(v);
        }
      }
    }
  }
}

__global__ __launch_bounds__(256) void qkv_gemm_kernel(
    const short* __restrict__ X,
    const short* __restrict__ Wq, const short* __restrict__ Wk, const short* __restrict__ Wv,
    const float* __restrict__ bq, const float* __restrict__ bk, const float* __restrict__ bv,
    short* __restrict__ Q, short* __restrict__ K, short* __restrict__ V)
{
  const int z = blockIdx.z;
  if (z == 0)      gemm_bt_body<0>(X, Wq, bq, Q, D_MODEL, D_MODEL);
  else if (z == 1) gemm_bt_body<0>(X, Wk, bk, K, D_MODEL, D_MODEL);
  else             gemm_bt_body<2>(X, Wv, bv, V, D_MODEL, D_MODEL);
}

__global__ __launch_bounds__(256) void out_gemm_kernel(
    const short* __restrict__ Ctx, const short* __restrict__ Wo,
    const float* __restrict__ bo, float* __restrict__ Out)
{
  gemm_bt_body<1>(Ctx, Wo, bo, Out, D_MODEL, D_MODEL);
}

// ---------------- flash attention, swapped-operand structure ----------------
// S^T = K·Q^T per tile: lane holds q = lane&15 (one q), 16 keys in regs.
// Softmax: in-lane reduce + 2 shfl. PV: ctx^T += mfma16x16x16(V^T-frag, P-pack).
__global__ __launch_bounds__(256) void attn_kernel(
    const short* __restrict__ Qb, const short* __restrict__ Kb,
    const short* __restrict__ Vtg, const int* __restrict__ mask,
    const float* __restrict__ rel_table, short* __restrict__ Ctx)
{
  const int bid = blockIdx.x;
  const int xcd = bid & 7, slot = bid >> 3;
  const int bh = xcd * 8 + (slot >> 4);      // 8 (b,h) groups per XCD
  const int qt = slot & 15;
  const int b = bh >> 4, h = bh & 15;
  const int q0 = qt * 64;
  const int tid = threadIdx.x, lane = tid & 63, w = tid >> 6;
  const int fr = lane & 15, g = lane >> 4;

  __shared__ short Ks[2][64][64];   // [key][dim], XOR-swizzled bytes
  __shared__ short Vs[2][64][64];   // [dim][key], XOR-swizzled bytes
  __shared__ float rel_sh[128];     // per-head bias, pre-scaled by log2e
  __shared__ float maskf[2][64];    // 0/1 per key, double-buffered

  for (int i = tid; i < 127; i += 256) rel_sh[i] = rel_table[i * N_HEADS + h] * LOG2E;
  const float cb_lo = rel_table[0*N_HEADS + h]   * LOG2E;   // d clamped to 0
  const float cb_hi = rel_table[126*N_HEADS + h] * LOG2E;   // d clamped to 126

  const short* Qg = Qb + (size_t)b*SEQ*D_MODEL + h*D_KK;
  const short* Kg = Kb + (size_t)b*SEQ*D_MODEL + h*D_KK;
  const short* Vg = Vtg + (size_t)bh*D_KK*SEQ;     // rows = d (stride SEQ)

  // Q fragment (B-operand): lane holds col q=fr, k=g*8+j (+f*32)
  const int q = q0 + w*16 + fr;
  short8 qf[2];
  #pragma unroll
  for (int f=0; f<2; f++)
    qf[f] = *reinterpret_cast<const short8*>(Qg + (size_t)q*D_MODEL + g*8 + f*32);

  f32x4 ctx[4];   // ctx^T: lane holds q=fr, d = dt*16 + g*4 + r
  #pragma unroll
  for (int dt=0; dt<4; dt++) ctx[dt] = (f32x4){0.f,0.f,0.f,0.f};
  float mrun = -3.0e38f, lrun = 0.f;

  const int srow = lane >> 3;
  const int scol = ((lane & 7) ^ srow) * 8;   // pre-swizzled 16B column
  auto stage = [&](int buf, int kv0){
    #pragma unroll
    for (int i=0;i<2;i++){
      const int c = w*2 + i;
      gl2lds16(Kg + (size_t)(kv0 + c*8 + srow)*D_MODEL + scol, &Ks[buf][c*8][0]);
      gl2lds16(Vg + (size_t)(c*8 + srow)*SEQ + kv0 + scol,     &Vs[buf][c*8][0]);
    }
    if (tid < 64)
      maskf[buf][tid] = mask[b*SEQ + kv0 + tid] ? 1.f : 0.f;
  };

  stage(0, 0);
  __syncthreads();

  int buf = 0;
  for (int t = 0; t < SEQ/64; ++t){
    const int kv0 = t * 64;
    if (t < SEQ/64 - 1) stage(buf ^ 1, kv0 + 64);

    // QK^T swapped: sc[kt] = K-tile · Q^T -> S^T[key][q]
    const char* ksb = (const char*)&Ks[buf][0][0];
    f32x4 sc[4];
    #pragma unroll
    for (int kt=0;kt<4;kt++){
      sc[kt] = (f32x4){0.f,0.f,0.f,0.f};
      const int rr = kt*16 + fr;
      const int swz = (rr & 7) << 4;
      #pragma unroll
      for (int f=0;f<2;f++){
        short8 kf = *reinterpret_cast<const short8*>(
            ksb + rr*128 + ((g*16 + f*64) ^ swz));
        sc[kt] = __builtin_amdgcn_mfma_f32_16x16x32_bf16(kf, qf[f], sc[kt], 0,0,0);
      }
    }
    // per lane: sc[kt][r] = score(key = kv0+kt*16+g*4+r, q)

    // scale + bias + mask (log2 domain)
    const int delta = kv0 - q0;
    if (delta >= 128 || delta <= -128){
      const float cb = (delta > 0) ? cb_hi : cb_lo;
      #pragma unroll
      for (int kt=0;kt<4;kt++){
        f32x4 mk4 = *reinterpret_cast<const f32x4*>(&maskf[buf][kt*16 + g*4]);
        #pragma unroll
        for (int r=0;r<4;r++){
          float s2 = fmaf(sc[kt][r], SCALE2, cb);
          sc[kt][r] = (mk4[r] != 0.f) ? s2 : NEGBIG;
        }
      }
    } else {
      const int dbase = delta + 63 - (w*16 + fr);
      #pragma unroll
      for (int kt=0;kt<4;kt++){
        f32x4 mk4 = *reinterpret_cast<const f32x4*>(&maskf[buf][kt*16 + g*4]);
        #pragma unroll
        for (int r=0;r<4;r++){
          int d = dbase + kt*16 + g*4 + r;
          d = d < 0 ? 0 : (d > 126 ? 126 : d);
          float s2 = fmaf(sc[kt][r], SCALE2, rel_sh[d]);
          sc[kt][r] = (mk4[r] != 0.f) ? s2 : NEGBIG;
        }
      }
    }

    // online softmax: in-lane over 16 keys, then xor16/xor32 across groups
    float tmax = sc[0][0];
    #pragma unroll
    for (int kt=0;kt<4;kt++)
      #pragma unroll
      for (int r=0;r<4;r++) tmax = fmaxf(tmax, sc[kt][r]);
    tmax = fmaxf(tmax, __shfl_xor(tmax, 16));
    tmax = fmaxf(tmax, __shfl_xor(tmax, 32));
    const float mnew = fmaxf(mrun, tmax);
    const float corr = exp2f(mrun - mnew);
    float psum = 0.f;
    #pragma unroll
    for (int kt=0;kt<4;kt++)
      #pragma unroll
      for (int r=0;r<4;r++){
        float p = exp2f(sc[kt][r] - mnew);
        sc[kt][r] = p;
        psum += p;
      }
    psum += __shfl_xor(psum, 16);
    psum += __shfl_xor(psum, 32);
    lrun = lrun*corr + psum;
    mrun = mnew;
    #pragma unroll
    for (int dt=0;dt<4;dt++)
      #pragma unroll
      for (int r=0;r<4;r++) ctx[dt][r] *= corr;

    // PV: ctx^T[d][q] += V^T[d][k] * P^T[k][q]
    const char* vsb = (const char*)&Vs[buf][0][0];
#if HAVE_MFMA16
    short4v pa[4];
    #pragma unroll
    for (int kt=0;kt<4;kt++){
      union { short4v s; __hip_bfloat162 h[2]; } u;
      u.h[0] = __float22bfloat162_rn(make_float2(sc[kt][0], sc[kt][1]));
      u.h[1] = __float22bfloat162_rn(make_float2(sc[kt][2], sc[kt][3]));
      pa[kt] = u.s;
    }
    #pragma unroll
    for (int dt=0;dt<4;dt++){
      const int dr = dt*16 + fr;
      const int dswz = dr & 7;
      #pragma unroll
      for (int kt=0;kt<4;kt++){
        const int voff = (((kt*2 + (g>>1)) ^ dswz) << 4) + ((g&1)*8);
        short4v va = *reinterpret_cast<const short4v*>(vsb + dr*128 + voff);
        ctx[dt] = __builtin_amdgcn_mfma_f32_16x16x16bf16_1k(va, pa[kt], ctx[dt], 0,0,0);
      }
    }
#else
    // fallback: build K=32 B-frags via shfl from packed pairs
    unsigned pk[4][2];
    #pragma unroll
    for (int kt=0;kt<4;kt++){
      union { unsigned u; __hip_bfloat162 h; } u0, u1;
      u0.h = __float22bfloat162_rn(make_float2(sc[kt][0], sc[kt][1]));
      u1.h = __float22bfloat162_rn(make_float2(sc[kt][2], sc[kt][3]));
      pk[kt][0] = u0.u; pk[kt][1] = u1.u;
    }
    #pragma unroll
    for (int f=0;f<2;f++){
      union { short8 s8; unsigned u[4]; } bfrag;
      #pragma unroll
      for (int m=0;m<4;m++){
        const int srcl = ((g&1)*2 + (m>>1))*16 + fr;
        unsigned a0 = __shfl((int)pk[f*2+0][m&1], srcl);
        unsigned a1 = __shfl((int)pk[f*2+1][m&1], srcl);
        bfrag.u[m] = (g >> 1) ? a1 : a0;
      }
      #pragma unroll
      for (int dt=0;dt<4;dt++){
        const int dr = dt*16 + fr;
        const int vswz = (dr & 7) << 4;
        short8 va = *reinterpret_cast<const short8*>(
            vsb + dr*128 + ((g*16 + f*64) ^ vswz));
        ctx[dt] = __builtin_amdgcn_mfma_f32_16x16x32_bf16(va, bfrag.s8, ctx[dt], 0,0,0);
      }
    }
#endif

    __syncthreads();
    buf ^= 1;
  }

  const float rl = 1.f / lrun;
  #pragma unroll
  for (int dt=0;dt<4;dt++){
    short4v o;
    #pragma unroll
    for (int r=0;r<4;r++) o[r] = f2b(ctx[dt][r] * rl);
    *reinterpret_cast<short4v*>(
        Ctx + (size_t)(b*SEQ + q)*D_MODEL + h*D_KK + dt*16 + g*4) = o;
  }
}

// ---------------- launch ----------------
extern "C" void kernel_launch(void* const* d_in, const int* in_sizes, int n_in,
                              void* d_out, int out_size, void* d_ws, size_t ws_size,
                              hipStream_t stream) {
  const float* x    = (const float*)d_in[0];
  const int*   mask = (const int*)  d_in[1];
  const float* wq   = (const float*)d_in[2];
  const float* bq   = (const float*)d_in[3];
  const float* wk   = (const float*)d_in[4];
  const float* bk   = (const float*)d_in[5];
  const float* wv   = (const float*)d_in[6];
  const float* bv   = (const float*)d_in[7];
  const float* wo   = (const float*)d_in[8];
  const float* bo   = (const float*)d_in[9];
  const float* rel  = (const float*)d_in[10];

  const size_t NX = (size_t)NTOK * D_MODEL;      // 4194304
  const size_t NW = (size_t)D_MODEL * D_MODEL;   // 1048576
  if (ws_size < (NX + 4*NW + 4*NX) * sizeof(short)) return;
  short* xb   = (short*)d_ws;
  short* wqb  = xb  + NX;
  short* wkb  = wqb + NW;
  short* wvb  = wkb + NW;
  short* wob  = wvb + NW;
  short* Qb   = wob + NW;
  short* Kb   = Qb  + NX;
  short* Vtg  = Kb  + NX;   // V transposed per head: [B*H][64][SEQ]
  short* Ctxb = Vtg + NX;

  cvt_kernel<<<4096, 256, 0, stream>>>(x,  xb,  (int)NX);
  cvt_kernel<<<1024, 256, 0, stream>>>(wq, wqb, (int)NW);
  cvt_kernel<<<1024, 256, 0, stream>>>(wk, wkb, (int)NW);
  cvt_kernel<<<1024, 256, 0, stream>>>(wv, wvb, (int)NW);
  cvt_kernel<<<1024, 256, 0, stream>>>(wo, wob, (int)NW);

  qkv_gemm_kernel<<<dim3(8, 32, 3), 256, 0, stream>>>(
      xb, wqb, wkb, wvb, bq, bk, bv, Qb, Kb, Vtg);

  attn_kernel<<<1024, 256, 0, stream>>>(Qb, Kb, Vtg, mask, rel, Ctxb);

  out_gemm_kernel<<<dim3(8, 32), 256, 0, stream>>>(Ctxb, wob, bo, (float*)d_out);
}

// Round 4
// 137.600 us; speedup vs baseline: 1.2196x; 1.0764x over previous
//
#include <hip/hip_runtime.h>
#include <hip/hip_bf16.h>

typedef __attribute__((ext_vector_type(8))) short short8;
typedef __attribute__((ext_vector_type(4))) short short4v;
typedef __attribute__((ext_vector_type(4))) float f32x4;

#define D_MODEL 1024
#define N_HEADS 16
#define D_KK 64
#define BATCH 4
#define SEQ 1024
#define NTOK (BATCH*SEQ)

#define LOG2E  1.44269504f
#define SCALE2 (0.125f * 1.44269504f)
#define NEGBIG (-1.44269504e9f)

#if __has_builtin(__builtin_amdgcn_mfma_f32_16x16x16bf16_1k)
#define HAVE_MFMA16 1
#else
#define HAVE_MFMA16 0
#endif

// round-to-nearest-even f32 -> bf16 (bit pattern in short)
__device__ __forceinline__ short f2b(float f){
  unsigned u = __float_as_uint(f);
  u += 0x7fffu + ((u >> 16) & 1u);
  return (short)(u >> 16);
}

__device__ __forceinline__ void gl2lds16(const void* g, void* l){
  __builtin_amdgcn_global_load_lds(
      (const __attribute__((address_space(1))) void*)g,
      (__attribute__((address_space(3))) void*)l, 16, 0, 0);
}

// ---------------- fused f32 -> bf16 conversion (x, wq, wk, wv, wo) ----------
// dst segments are contiguous: [xb | wqb | wkb | wvb | wob]
__global__ __launch_bounds__(256) void cvt_all_kernel(
    const float* __restrict__ x,  const float* __restrict__ wq,
    const float* __restrict__ wk, const float* __restrict__ wv,
    const float* __restrict__ wo, short* __restrict__ dst)
{
  const size_t NX = (size_t)NTOK * D_MODEL;
  const size_t NW = (size_t)D_MODEL * D_MODEL;
  size_t e = ((size_t)blockIdx.x * 256 + threadIdx.x) * 4;
  const float* s;
  size_t off;
  if      (e < NX)        { s = x;  off = e; }
  else if (e < NX +   NW) { s = wq; off = e - NX; }
  else if (e < NX + 2*NW) { s = wk; off = e - NX -   NW; }
  else if (e < NX + 3*NW) { s = wv; off = e - NX - 2*NW; }
  else                    { s = wo; off = e - NX - 3*NW; }
  f32x4 v = *reinterpret_cast<const f32x4*>(s + off);
  short4v o;
  o[0]=f2b(v[0]); o[1]=f2b(v[1]); o[2]=f2b(v[2]); o[3]=f2b(v[3]);
  *reinterpret_cast<short4v*>(dst + e) = o;
}

// ---------------- GEMM: C[M,N] = A[M,K] @ W[N,K]^T + bias ----------------
// 128x128 tile, BK=32, 4 waves (2x2), each wave 64x64 (4x4 frags of 16x16x32)
// MODE 0: bf16 row-major out. MODE 1: f32 row-major out.
// MODE 2: bf16 out transposed per head: Out[((b*16+h)*64 + d)*SEQ + s]
template<int MODE>
__device__ __forceinline__ void gemm_bt_body(const short* __restrict__ A,
    const short* __restrict__ W, const float* __restrict__ bias,
    void* __restrict__ Cout, int N, int K)
{
  __shared__ short As[128][32];
  __shared__ short Bs[128][32];
  const int tid = threadIdx.x, lane = tid & 63, w = tid >> 6;
  const int wr = w >> 1, wc = w & 1;
  const int bn0 = blockIdx.x * 128, bm0 = blockIdx.y * 128;
  const int lrow = lane >> 2, lcol = (lane & 3) * 8;
  const int fr = lane & 15, fk = (lane >> 4) * 8;

  f32x4 acc[4][4];
  #pragma unroll
  for (int m=0;m<4;m++)
    #pragma unroll
    for (int n=0;n<4;n++) acc[m][n] = (f32x4){0.f,0.f,0.f,0.f};

  for (int k0 = 0; k0 < K; k0 += 32){
    __syncthreads();
    #pragma unroll
    for (int i=0;i<2;i++){
      const int c = w*2 + i;
      gl2lds16(A + (size_t)(bm0 + c*16 + lrow)*K + k0 + lcol, &As[c*16][0]);
      gl2lds16(W + (size_t)(bn0 + c*16 + lrow)*K + k0 + lcol, &Bs[c*16][0]);
    }
    __syncthreads();
    short8 af[4], bfr[4];
    #pragma unroll
    for (int m=0;m<4;m++)
      af[m] = *reinterpret_cast<const short8*>(&As[wr*64 + m*16 + fr][fk]);
    #pragma unroll
    for (int n=0;n<4;n++)
      bfr[n] = *reinterpret_cast<const short8*>(&Bs[wc*64 + n*16 + fr][fk]);
    #pragma unroll
    for (int m=0;m<4;m++)
      #pragma unroll
      for (int n=0;n<4;n++)
        acc[m][n] = __builtin_amdgcn_mfma_f32_16x16x32_bf16(af[m], bfr[n], acc[m][n], 0,0,0);
  }

  const int g4 = lane >> 4;
  #pragma unroll
  for (int n=0;n<4;n++){
    const int col = bn0 + wc*64 + n*16 + fr;
    const float bv = bias[col];
    if (MODE == 2){
      const int hh = col >> 6, dd = col & 63;
      #pragma unroll
      for (int m=0;m<4;m++){
        const int row0 = bm0 + wr*64 + m*16 + g4*4;
        const int bb = row0 >> 10, ss = row0 & 1023;
        short4v o;
        #pragma unroll
        for (int r=0;r<4;r++) o[r] = f2b(acc[m][n][r] + bv);
        *reinterpret_cast<short4v*>(
            (short*)Cout + ((size_t)(bb*N_HEADS+hh)*D_KK + dd)*SEQ + ss) = o;
      }
    } else {
      #pragma unroll
      for (int m=0;m<4;m++){
        const int row0 = bm0 + wr*64 + m*16 + g4*4;
        #pragma unroll
        for (int r=0;r<4;r++){
          float v = acc[m][n][r] + bv;
          if (MODE == 1) ((float*)Cout)[(size_t)(row0+r)*N + col] = v;
          else           ((short*)Cout)[(size_t)(row0+r)*N + col] = f2b(v);
        }
      }
    }
  }
}

__global__ __launch_bounds__(256) void qkv_gemm_kernel(
    const short* __restrict__ X,
    const short* __restrict__ Wq, const short* __restrict__ Wk, const short* __restrict__ Wv,
    const float* __restrict__ bq, const float* __restrict__ bk, const float* __restrict__ bv,
    short* __restrict__ Q, short* __restrict__ K, short* __restrict__ V)
{
  const int z = blockIdx.z;
  if (z == 0)      gemm_bt_body<0>(X, Wq, bq, Q, D_MODEL, D_MODEL);
  else if (z == 1) gemm_bt_body<0>(X, Wk, bk, K, D_MODEL, D_MODEL);
  else             gemm_bt_body<2>(X, Wv, bv, V, D_MODEL, D_MODEL);
}

__global__ __launch_bounds__(256) void out_gemm_kernel(
    const short* __restrict__ Ctx, const short* __restrict__ Wo,
    const float* __restrict__ bo, float* __restrict__ Out)
{
  gemm_bt_body<1>(Ctx, Wo, bo, Out, D_MODEL, D_MODEL);
}

// ---------------- flash attention, swapped-operand, 2 q-frags/wave ---------
// S^T = K·Q^T per tile: lane holds q = lane&15 within frag, 16 keys in regs.
// Each wave owns 32 q-rows (2 frags); K/V LDS reads amortize over both.
__global__ __launch_bounds__(256) void attn_kernel(
    const short* __restrict__ Qb, const short* __restrict__ Kb,
    const short* __restrict__ Vtg, const int* __restrict__ mask,
    const float* __restrict__ rel_table, short* __restrict__ Ctx)
{
  const int bid = blockIdx.x;
  const int xcd = bid & 7, slot = bid >> 3;
  const int bh = xcd * 8 + (slot >> 3);      // 8 (b,h) groups per XCD
  const int qt = slot & 7;                   // 8 q-tiles of 128 rows
  const int b = bh >> 4, h = bh & 15;
  const int q0 = qt * 128;
  const int tid = threadIdx.x, lane = tid & 63, w = tid >> 6;
  const int fr = lane & 15, g = lane >> 4;

  __shared__ short Ks[2][64][64];   // [key][dim], XOR-swizzled bytes
  __shared__ short Vs[2][64][64];   // [dim][key], XOR-swizzled bytes
  __shared__ float rel_sh[128];     // per-head bias, pre-scaled by log2e
  __shared__ float maskf[2][64];    // 0/1 per key, double-buffered

  for (int i = tid; i < 127; i += 256) rel_sh[i] = rel_table[i * N_HEADS + h] * LOG2E;
  const float cb_lo = rel_table[0*N_HEADS + h]   * LOG2E;   // d clamped to 0
  const float cb_hi = rel_table[126*N_HEADS + h] * LOG2E;   // d clamped to 126

  const short* Qg = Qb + (size_t)b*SEQ*D_MODEL + h*D_KK;
  const short* Kg = Kb + (size_t)b*SEQ*D_MODEL + h*D_KK;
  const short* Vg = Vtg + (size_t)bh*D_KK*SEQ;     // rows = d (stride SEQ)

  // two q's per lane: frag A = q0+w*32+fr, frag B = +16
  const int qa = q0 + w*32 + fr;
  const int qb = qa + 16;
  short8 qfa[2], qfb[2];
  #pragma unroll
  for (int f=0; f<2; f++){
    qfa[f] = *reinterpret_cast<const short8*>(Qg + (size_t)qa*D_MODEL + g*8 + f*32);
    qfb[f] = *reinterpret_cast<const short8*>(Qg + (size_t)qb*D_MODEL + g*8 + f*32);
  }

  f32x4 ctxa[4], ctxb[4];   // ctx^T: lane holds its q, d = dt*16 + g*4 + r
  #pragma unroll
  for (int dt=0; dt<4; dt++){ ctxa[dt] = (f32x4){0.f,0.f,0.f,0.f}; ctxb[dt] = ctxa[dt]; }
  float mruna = -3.0e38f, lruna = 0.f, mrunb = -3.0e38f, lrunb = 0.f;

  const int srow = lane >> 3;
  const int scol = ((lane & 7) ^ srow) * 8;   // pre-swizzled 16B column
  auto stage = [&](int buf, int kv0){
    #pragma unroll
    for (int i=0;i<2;i++){
      const int c = w*2 + i;
      gl2lds16(Kg + (size_t)(kv0 + c*8 + srow)*D_MODEL + scol, &Ks[buf][c*8][0]);
      gl2lds16(Vg + (size_t)(c*8 + srow)*SEQ + kv0 + scol,     &Vs[buf][c*8][0]);
    }
    if (tid < 64)
      maskf[buf][tid] = mask[b*SEQ + kv0 + tid] ? 1.f : 0.f;
  };

  stage(0, 0);
  __syncthreads();

  int buf = 0;
  for (int t = 0; t < SEQ/64; ++t){
    const int kv0 = t * 64;
    if (t < SEQ/64 - 1) stage(buf ^ 1, kv0 + 64);

    // QK^T swapped: sc = K-tile · Q^T -> S^T[key][q], two q-frags share kf
    const char* ksb = (const char*)&Ks[buf][0][0];
    f32x4 sca[4], scb[4];
    #pragma unroll
    for (int kt=0;kt<4;kt++){
      sca[kt] = (f32x4){0.f,0.f,0.f,0.f};
      scb[kt] = (f32x4){0.f,0.f,0.f,0.f};
      const int rr = kt*16 + fr;
      const int swz = (rr & 7) << 4;
      #pragma unroll
      for (int f=0;f<2;f++){
        short8 kf = *reinterpret_cast<const short8*>(
            ksb + rr*128 + ((g*16 + f*64) ^ swz));
        sca[kt] = __builtin_amdgcn_mfma_f32_16x16x32_bf16(kf, qfa[f], sca[kt], 0,0,0);
        scb[kt] = __builtin_amdgcn_mfma_f32_16x16x32_bf16(kf, qfb[f], scb[kt], 0,0,0);
      }
    }
    // per lane: sc[kt][r] = score(key = kv0+kt*16+g*4+r, q)

    // scale + bias + mask (log2 domain). q-block spans 128 rows:
    // gather needed for delta in {-64,0,64,128}; else clamped constant.
    const int delta = kv0 - q0;
    if (delta <= -128 || delta >= 192){
      const float cb = (delta > 0) ? cb_hi : cb_lo;
      #pragma unroll
      for (int kt=0;kt<4;kt++){
        f32x4 mk4 = *reinterpret_cast<const f32x4*>(&maskf[buf][kt*16 + g*4]);
        #pragma unroll
        for (int r=0;r<4;r++){
          float sa = fmaf(sca[kt][r], SCALE2, cb);
          float sb = fmaf(scb[kt][r], SCALE2, cb);
          sca[kt][r] = (mk4[r] != 0.f) ? sa : NEGBIG;
          scb[kt][r] = (mk4[r] != 0.f) ? sb : NEGBIG;
        }
      }
    } else {
      const int dba = delta + 63 - (w*32 + fr);       // frag A base
      #pragma unroll
      for (int kt=0;kt<4;kt++){
        f32x4 mk4 = *reinterpret_cast<const f32x4*>(&maskf[buf][kt*16 + g*4]);
        #pragma unroll
        for (int r=0;r<4;r++){
          int da = dba + kt*16 + g*4 + r;
          int db = da - 16;
          da = da < 0 ? 0 : (da > 126 ? 126 : da);
          db = db < 0 ? 0 : (db > 126 ? 126 : db);
          float sa = fmaf(sca[kt][r], SCALE2, rel_sh[da]);
          float sb = fmaf(scb[kt][r], SCALE2, rel_sh[db]);
          sca[kt][r] = (mk4[r] != 0.f) ? sa : NEGBIG;
          scb[kt][r] = (mk4[r] != 0.f) ? sb : NEGBIG;
        }
      }
    }

    // online softmax per frag: in-lane over 16 keys, xor16/xor32, defer-max
    {
      float tmax = sca[0][0];
      #pragma unroll
      for (int kt=0;kt<4;kt++)
        #pragma unroll
        for (int r=0;r<4;r++) tmax = fmaxf(tmax, sca[kt][r]);
      tmax = fmaxf(tmax, __shfl_xor(tmax, 16));
      tmax = fmaxf(tmax, __shfl_xor(tmax, 32));
      if (!__all(tmax <= mruna + 8.f)){
        const float mnew = fmaxf(mruna, tmax);
        const float corr = exp2f(mruna - mnew);
        lruna *= corr;
        #pragma unroll
        for (int dt=0;dt<4;dt++)
          #pragma unroll
          for (int r=0;r<4;r++) ctxa[dt][r] *= corr;
        mruna = mnew;
      }
      float psum = 0.f;
      #pragma unroll
      for (int kt=0;kt<4;kt++)
        #pragma unroll
        for (int r=0;r<4;r++){
          float p = exp2f(sca[kt][r] - mruna);
          sca[kt][r] = p;
          psum += p;
        }
      psum += __shfl_xor(psum, 16);
      psum += __shfl_xor(psum, 32);
      lruna += psum;
    }
    {
      float tmax = scb[0][0];
      #pragma unroll
      for (int kt=0;kt<4;kt++)
        #pragma unroll
        for (int r=0;r<4;r++) tmax = fmaxf(tmax, scb[kt][r]);
      tmax = fmaxf(tmax, __shfl_xor(tmax, 16));
      tmax = fmaxf(tmax, __shfl_xor(tmax, 32));
      if (!__all(tmax <= mrunb + 8.f)){
        const float mnew = fmaxf(mrunb, tmax);
        const float corr = exp2f(mrunb - mnew);
        lrunb *= corr;
        #pragma unroll
        for (int dt=0;dt<4;dt++)
          #pragma unroll
          for (int r=0;r<4;r++) ctxb[dt][r] *= corr;
        mrunb = mnew;
      }
      float psum = 0.f;
      #pragma unroll
      for (int kt=0;kt<4;kt++)
        #pragma unroll
        for (int r=0;r<4;r++){
          float p = exp2f(scb[kt][r] - mrunb);
          scb[kt][r] = p;
          psum += p;
        }
      psum += __shfl_xor(psum, 16);
      psum += __shfl_xor(psum, 32);
      lrunb += psum;
    }

    // PV: ctx^T[d][q] += V^T[d][k] * P^T[k][q]; V-frags shared by both frags
    const char* vsb = (const char*)&Vs[buf][0][0];
#if HAVE_MFMA16
    short4v paa[4], pab[4];
    #pragma unroll
    for (int kt=0;kt<4;kt++){
      union { short4v s; __hip_bfloat162 h[2]; } ua, ub;
      ua.h[0] = __float22bfloat162_rn(make_float2(sca[kt][0], sca[kt][1]));
      ua.h[1] = __float22bfloat162_rn(make_float2(sca[kt][2], sca[kt][3]));
      ub.h[0] = __float22bfloat162_rn(make_float2(scb[kt][0], scb[kt][1]));
      ub.h[1] = __float22bfloat162_rn(make_float2(scb[kt][2], scb[kt][3]));
      paa[kt] = ua.s; pab[kt] = ub.s;
    }
    #pragma unroll
    for (int dt=0;dt<4;dt++){
      const int dr = dt*16 + fr;
      const int dswz = dr & 7;
      #pragma unroll
      for (int kt=0;kt<4;kt++){
        const int voff = (((kt*2 + (g>>1)) ^ dswz) << 4) + ((g&1)*8);
        short4v va = *reinterpret_cast<const short4v*>(vsb + dr*128 + voff);
        ctxa[dt] = __builtin_amdgcn_mfma_f32_16x16x16bf16_1k(va, paa[kt], ctxa[dt], 0,0,0);
        ctxb[dt] = __builtin_amdgcn_mfma_f32_16x16x16bf16_1k(va, pab[kt], ctxb[dt], 0,0,0);
      }
    }
#else
    // fallback: build K=32 B-frags via shfl from packed pairs
    unsigned pka[4][2], pkb[4][2];
    #pragma unroll
    for (int kt=0;kt<4;kt++){
      union { unsigned u; __hip_bfloat162 h; } u0, u1;
      u0.h = __float22bfloat162_rn(make_float2(sca[kt][0], sca[kt][1]));
      u1.h = __float22bfloat162_rn(make_float2(sca[kt][2], sca[kt][3]));
      pka[kt][0] = u0.u; pka[kt][1] = u1.u;
      u0.h = __float22bfloat162_rn(make_float2(scb[kt][0], scb[kt][1]));
      u1.h = __float22bfloat162_rn(make_float2(scb[kt][2], scb[kt][3]));
      pkb[kt][0] = u0.u; pkb[kt][1] = u1.u;
    }
    #pragma unroll
    for (int f=0;f<2;f++){
      union { short8 s8; unsigned u[4]; } bfa, bfb;
      #pragma unroll
      for (int m=0;m<4;m++){
        const int srcl = ((g&1)*2 + (m>>1))*16 + fr;
        unsigned a0 = __shfl((int)pka[f*2+0][m&1], srcl);
        unsigned a1 = __shfl((int)pka[f*2+1][m&1], srcl);
        bfa.u[m] = (g >> 1) ? a1 : a0;
        unsigned b0 = __shfl((int)pkb[f*2+0][m&1], srcl);
        unsigned b1 = __shfl((int)pkb[f*2+1][m&1], srcl);
        bfb.u[m] = (g >> 1) ? b1 : b0;
      }
      #pragma unroll
      for (int dt=0;dt<4;dt++){
        const int dr = dt*16 + fr;
        const int vswz = (dr & 7) << 4;
        short8 va = *reinterpret_cast<const short8*>(
            vsb + dr*128 + ((g*16 + f*64) ^ vswz));
        ctxa[dt] = __builtin_amdgcn_mfma_f32_16x16x32_bf16(va, bfa.s8, ctxa[dt], 0,0,0);
        ctxb[dt] = __builtin_amdgcn_mfma_f32_16x16x32_bf16(va, bfb.s8, ctxb[dt], 0,0,0);
      }
    }
#endif

    __syncthreads();
    buf ^= 1;
  }

  const float rla = 1.f / lruna, rlb = 1.f / lrunb;
  #pragma unroll
  for (int dt=0;dt<4;dt++){
    short4v oa, ob;
    #pragma unroll
    for (int r=0;r<4;r++){ oa[r] = f2b(ctxa[dt][r] * rla); ob[r] = f2b(ctxb[dt][r] * rlb); }
    *reinterpret_cast<short4v*>(
        Ctx + (size_t)(b*SEQ + qa)*D_MODEL + h*D_KK + dt*16 + g*4) = oa;
    *reinterpret_cast<short4v*>(
        Ctx + (size_t)(b*SEQ + qb)*D_MODEL + h*D_KK + dt*16 + g*4) = ob;
  }
}

// ---------------- launch ----------------
extern "C" void kernel_launch(void* const* d_in, const int* in_sizes, int n_in,
                              void* d_out, int out_size, void* d_ws, size_t ws_size,
                              hipStream_t stream) {
  const float* x    = (const float*)d_in[0];
  const int*   mask = (const int*)  d_in[1];
  const float* wq   = (const float*)d_in[2];
  const float* bq   = (const float*)d_in[3];
  const float* wk   = (const float*)d_in[4];
  const float* bk   = (const float*)d_in[5];
  const float* wv   = (const float*)d_in[6];
  const float* bv   = (const float*)d_in[7];
  const float* wo   = (const float*)d_in[8];
  const float* bo   = (const float*)d_in[9];
  const float* rel  = (const float*)d_in[10];

  const size_t NX = (size_t)NTOK * D_MODEL;      // 4194304
  const size_t NW = (size_t)D_MODEL * D_MODEL;   // 1048576
  if (ws_size < (NX + 4*NW + 4*NX) * sizeof(short)) return;
  short* xb   = (short*)d_ws;
  short* wqb  = xb  + NX;
  short* wkb  = wqb + NW;
  short* wvb  = wkb + NW;
  short* wob  = wvb + NW;
  short* Qb   = wob + NW;
  short* Kb   = Qb  + NX;
  short* Vtg  = Kb  + NX;   // V transposed per head: [B*H][64][SEQ]
  short* Ctxb = Vtg + NX;

  cvt_all_kernel<<<8192, 256, 0, stream>>>(x, wq, wk, wv, wo, xb);

  qkv_gemm_kernel<<<dim3(8, 32, 3), 256, 0, stream>>>(
      xb, wqb, wkb, wvb, bq, bk, bv, Qb, Kb, Vtg);

  attn_kernel<<<512, 256, 0, stream>>>(Qb, Kb, Vtg, mask, rel, Ctxb);

  out_gemm_kernel<<<dim3(8, 32), 256, 0, stream>>>(Ctxb, wob, bo, (float*)d_out);
}